// Round 8
// baseline (189.388 us; speedup 1.0000x reference)
//
#include <hip/hip_runtime.h>
#include <hip/hip_bf16.h>

// Shapes (fixed by the reference)
#define BB 32          // batch
#define CC 1024        // channels
#define HWSZ 576       // H*W
#define KCTX 8         // CONTEXT_LEN
#define TT 9           // K+1
#define NH 8
#define HD 128

#define NS 4           // split-K for both projections (k-slice 256)
#define KV_MN (288 * 2048)
#define Q_MN  (32 * 1024)

typedef float v4f __attribute__((ext_vector_type(4)));
typedef __attribute__((ext_vector_type(8))) short  bf16x8;
typedef __attribute__((ext_vector_type(8))) ushort u16x8;
typedef __attribute__((ext_vector_type(4))) float  f32x4;

__device__ __forceinline__ ushort f2bf(float f) {
    uint u = __builtin_bit_cast(uint, f);
    return (ushort)((u + 0x7FFFu + ((u >> 16) & 1u)) >> 16);   // RNE
}

// ---------------------------------------------------------------------------
// K1: spatial mean pooling -> context [B][T][C] in BF16, plus W_qkv fp32->bf16
// conversion tail. 16 lanes per row, 4 rows per wave. Buffer rows first in
// memory order (NORMAL cached loads — A/B vs R7's nontemporal; h_current
// L3-residency is guaranteed by ordering, not by NT); h_current rows last.
// ---------------------------------------------------------------------------
__global__ __launch_bounds__(256) void pool_kernel(
    const float* __restrict__ hbuf,   // [K][B][C][H][W]
    const float* __restrict__ hcur,   // [B][C][H][W]
    const float* __restrict__ Wqkv,   // [3072][1024] fp32
    ushort* __restrict__ ctxb,        // [B][T][C] bf16
    ushort* __restrict__ Wb)          // [3072][1024] bf16
{
    const int wave = threadIdx.x >> 6;
    const int lane = threadIdx.x & 63;
    const int sub  = lane >> 4;        // row-within-wave 0..3
    const int l16  = lane & 15;
    const int stride = gridDim.x * 16; // rows per full sweep
    const int nrows = BB * TT * CC;    // 294912

    for (int r0 = (blockIdx.x * 4 + wave) * 4; r0 < nrows; r0 += stride) {
        const int r = r0 + sub;
        v4f acc = {0.f, 0.f, 0.f, 0.f};
        int cidx;
        if (r < KCTX * BB * CC) {                 // buffer rows, memory order
            const v4f* s4 = (const v4f*)(hbuf + (size_t)r * HWSZ);
            const int t = r >> 15;
            const int b = (r >> 10) & 31;
            cidx = (b * TT + t) * CC + (r & (CC - 1));
#pragma unroll
            for (int j = 0; j < 9; ++j)
                acc += s4[l16 + 16 * j];
        } else {                                  // current rows, last, cached
            const int rc = r - KCTX * BB * CC;
            const v4f* s4 = (const v4f*)(hcur + (size_t)rc * HWSZ);
            cidx = ((rc >> 10) * TT + KCTX) * CC + (rc & (CC - 1));
#pragma unroll
            for (int j = 0; j < 9; ++j)
                acc += s4[l16 + 16 * j];
        }
        float sum = acc.x + acc.y + acc.z + acc.w;
        sum += __shfl_xor(sum, 1);
        sum += __shfl_xor(sum, 2);
        sum += __shfl_xor(sum, 4);
        sum += __shfl_xor(sum, 8);
        if (l16 == 0) ctxb[cidx] = f2bf(sum * (1.0f / 576.0f));
    }

    // W_qkv fp32 -> bf16 (3072*1024/8 = 393216 chunks of 8)
    const int nchunk = 3072 * 1024 / 8;
    for (int idx = blockIdx.x * 256 + threadIdx.x; idx < nchunk;
         idx += gridDim.x * 256) {
        const float* src = Wqkv + (size_t)idx * 8;
        v4f a = *(const v4f*)src;
        v4f b = *(const v4f*)(src + 4);
        u16x8 o;
        o[0] = f2bf(a.x); o[1] = f2bf(a.y); o[2] = f2bf(a.z); o[3] = f2bf(a.w);
        o[4] = f2bf(b.x); o[5] = f2bf(b.y); o[6] = f2bf(b.z); o[7] = f2bf(b.w);
        *(u16x8*)(Wb + (size_t)idx * 8) = o;
    }
}

// ---------------------------------------------------------------------------
// K2: Q + KV projections via bf16 MFMA (no LDS; A/B straight from L2).
// 1216 wave-tiles: [0,1152) KV (18 mt x 16 nt x 4 splits, tile 16x128),
// [1152,1216) Q (2 mt x 8 nt x 4 splits). Partials fp32.
// ---------------------------------------------------------------------------
__global__ __launch_bounds__(256) void qkv_mfma(
    const ushort* __restrict__ ctxb, const ushort* __restrict__ Wb,
    float* __restrict__ qpart, float* __restrict__ kvpart)
{
    const int wave = threadIdx.x >> 6;
    const int lane = threadIdx.x & 63;
    const int t = blockIdx.x * 4 + wave;   // 0..1215
    const int l15 = lane & 15;
    const int kg  = lane >> 4;             // 0..3

    const ushort* abase;
    const ushort* bbase;
    float* out;
    int ldy, outrow0, outcol0;

    if (t < 1152) {                        // KV tiles
        const int s  = t & 3;
        const int tt = t >> 2;             // 0..287
        const int mt = tt / 16, nt = tt % 16;
        const int k0 = s * 256;
        abase = ctxb + (size_t)(mt * 16 + l15) * 1024 + k0 + kg * 8;
        bbase = Wb + (size_t)(1024 + nt * 128 + l15) * 1024 + k0 + kg * 8;
        out = kvpart + (size_t)s * KV_MN;
        ldy = 2048;
        outrow0 = mt * 16 + kg * 4;
        outcol0 = nt * 128 + l15;
    } else {                               // Q tiles
        const int r  = t - 1152;           // 0..63
        const int s  = r & 3;
        const int tt = r >> 2;             // 0..15
        const int mt = tt >> 3, nt = tt & 7;
        const int k0 = s * 256;
        abase = ctxb + (size_t)((mt * 16 + l15) * 9 + 8) * 1024 + k0 + kg * 8;
        bbase = Wb + (size_t)(nt * 128 + l15) * 1024 + k0 + kg * 8;
        out = qpart + (size_t)s * Q_MN;
        ldy = 1024;
        outrow0 = mt * 16 + kg * 4;
        outcol0 = nt * 128 + l15;
    }

    f32x4 acc0 = {0,0,0,0}, acc1 = {0,0,0,0}, acc2 = {0,0,0,0}, acc3 = {0,0,0,0};
    f32x4 acc4 = {0,0,0,0}, acc5 = {0,0,0,0}, acc6 = {0,0,0,0}, acc7 = {0,0,0,0};

#pragma unroll
    for (int kk = 0; kk < 8; ++kk) {       // 8 k-steps of 32 (k-slice 256)
        bf16x8 a = *(const bf16x8*)(abase + kk * 32);
        const ushort* bp = bbase + kk * 32;
        bf16x8 b0 = *(const bf16x8*)(bp + 0 * 16 * 1024);
        bf16x8 b1 = *(const bf16x8*)(bp + 1 * 16 * 1024);
        bf16x8 b2 = *(const bf16x8*)(bp + 2 * 16 * 1024);
        bf16x8 b3 = *(const bf16x8*)(bp + 3 * 16 * 1024);
        bf16x8 b4 = *(const bf16x8*)(bp + 4 * 16 * 1024);
        bf16x8 b5 = *(const bf16x8*)(bp + 5 * 16 * 1024);
        bf16x8 b6 = *(const bf16x8*)(bp + 6 * 16 * 1024);
        bf16x8 b7 = *(const bf16x8*)(bp + 7 * 16 * 1024);
        acc0 = __builtin_amdgcn_mfma_f32_16x16x32_bf16(a, b0, acc0, 0, 0, 0);
        acc1 = __builtin_amdgcn_mfma_f32_16x16x32_bf16(a, b1, acc1, 0, 0, 0);
        acc2 = __builtin_amdgcn_mfma_f32_16x16x32_bf16(a, b2, acc2, 0, 0, 0);
        acc3 = __builtin_amdgcn_mfma_f32_16x16x32_bf16(a, b3, acc3, 0, 0, 0);
        acc4 = __builtin_amdgcn_mfma_f32_16x16x32_bf16(a, b4, acc4, 0, 0, 0);
        acc5 = __builtin_amdgcn_mfma_f32_16x16x32_bf16(a, b5, acc5, 0, 0, 0);
        acc6 = __builtin_amdgcn_mfma_f32_16x16x32_bf16(a, b6, acc6, 0, 0, 0);
        acc7 = __builtin_amdgcn_mfma_f32_16x16x32_bf16(a, b7, acc7, 0, 0, 0);
    }

    float* yb = out + (size_t)outrow0 * ldy + outcol0;
#pragma unroll
    for (int i = 0; i < 4; ++i) {
        float* yr = yb + (size_t)i * ldy;
        yr[0 * 16] = acc0[i]; yr[1 * 16] = acc1[i];
        yr[2 * 16] = acc2[i]; yr[3 * 16] = acc3[i];
        yr[4 * 16] = acc4[i]; yr[5 * 16] = acc5[i];
        yr[6 * 16] = acc6[i]; yr[7 * 16] = acc7[i];
    }
}

// ---------------------------------------------------------------------------
// K3: attention, last query only. One wave per block, 256 blocks.
// Sums split-K partials of q and kv inline (L2-hot).
// ---------------------------------------------------------------------------
__global__ __launch_bounds__(64) void attn_kernel(
    const float* __restrict__ kvpart,   // NS slabs of [288][2048]
    const float* __restrict__ qpart,    // NS slabs of [32][1024]
    const float* __restrict__ rel_emb,  // [17][8]
    float* __restrict__ attn_out)       // [B][C]
{
    const int lane = threadIdx.x;
    const int pair = blockIdx.x;              // 0..255
    const int b = pair >> 3;
    const int h = pair & 7;
    const float scale = 0.08838834764831845f; // 1/sqrt(128)

    const int qoff = b * CC + h * HD;
    float q1 = 0.f, q2 = 0.f;
#pragma unroll
    for (int s = 0; s < NS; ++s) {
        q1 += qpart[(size_t)s * Q_MN + qoff + lane];
        q2 += qpart[(size_t)s * Q_MN + qoff + lane + 64];
    }
    q1 *= scale; q2 *= scale;

    float sc[TT];
#pragma unroll
    for (int j = 0; j < TT; ++j) {
        const size_t base = (size_t)(b * TT + j) * 2048 + h * HD;
        float k1 = 0.f, k2 = 0.f;
#pragma unroll
        for (int s = 0; s < NS; ++s) {
            k1 += kvpart[(size_t)s * KV_MN + base + lane];
            k2 += kvpart[(size_t)s * KV_MN + base + lane + 64];
        }
        float p = q1 * k1 + q2 * k2;
#pragma unroll
        for (int off = 32; off; off >>= 1) p += __shfl_xor(p, off);
        sc[j] = p + rel_emb[(2 * KCTX - j) * NH + h];
    }
    float m = sc[0];
#pragma unroll
    for (int j = 1; j < TT; ++j) m = fmaxf(m, sc[j]);
    float sum = 0.f;
#pragma unroll
    for (int j = 0; j < TT; ++j) { sc[j] = expf(sc[j] - m); sum += sc[j]; }
    const float inv = 1.0f / sum;

    float a1 = 0.f, a2 = 0.f;
#pragma unroll
    for (int j = 0; j < TT; ++j) {
        const size_t base = (size_t)(b * TT + j) * 2048 + 1024 + h * HD;
        float v1 = 0.f, v2 = 0.f;
#pragma unroll
        for (int s = 0; s < NS; ++s) {
            v1 += kvpart[(size_t)s * KV_MN + base + lane];
            v2 += kvpart[(size_t)s * KV_MN + base + lane + 64];
        }
        a1 += sc[j] * v1;
        a2 += sc[j] * v2;
    }
    attn_out[qoff + lane] = a1 * inv;
    attn_out[qoff + lane + 64] = a2 * inv;
}

// ---------------------------------------------------------------------------
// K4: fused out-projection + broadcast residual add.
// One wave per output row: dot(attnb[b,:], Wout[c,:]) from L2, + bias,
// broadcast-add over 576 spatial floats (L3-hot h_current), NT store.
// ---------------------------------------------------------------------------
__global__ __launch_bounds__(256) void final_fused(
    const float* __restrict__ hc,       // [B][C][H][W]
    const float* __restrict__ attnb,    // [32][1024]
    const float* __restrict__ Wout,     // [1024][1024]
    const float* __restrict__ bias,     // [1024]
    float* __restrict__ y)
{
    const int wave = threadIdx.x >> 6;
    const int lane = threadIdx.x & 63;
    const int stride = gridDim.x * 4;
    const int nrows = BB * CC;

    for (int r = blockIdx.x * 4 + wave; r < nrows; r += stride) {
        const int b = r >> 10;
        const int c = r & (CC - 1);

        const v4f* ar = (const v4f*)(attnb + (size_t)b * CC);
        const v4f* wr = (const v4f*)(Wout + (size_t)c * CC);
        v4f acc = {0.f, 0.f, 0.f, 0.f};
#pragma unroll
        for (int j = 0; j < 4; ++j) {
            v4f a = ar[lane + 64 * j];
            v4f w = wr[lane + 64 * j];
            acc += a * w;
        }
        float dot = acc.x + acc.y + acc.z + acc.w;
#pragma unroll
        for (int off = 32; off; off >>= 1) dot += __shfl_xor(dot, off);
        const float add = dot + bias[c];

        const v4f* s4 = (const v4f*)(hc + (size_t)r * HWSZ);
        v4f* d4 = (v4f*)(y + (size_t)r * HWSZ);
        v4f v0 = s4[lane];
        v0.x += add; v0.y += add; v0.z += add; v0.w += add;
        __builtin_nontemporal_store(v0, d4 + lane);
        v4f v1 = s4[lane + 64];
        v1.x += add; v1.y += add; v1.z += add; v1.w += add;
        __builtin_nontemporal_store(v1, d4 + lane + 64);
        if (lane < 16) {
            v4f v2 = s4[lane + 128];
            v2.x += add; v2.y += add; v2.z += add; v2.w += add;
            __builtin_nontemporal_store(v2, d4 + lane + 128);
        }
    }
}

// ---------------------------------------------------------------------------
extern "C" void kernel_launch(void* const* d_in, const int* in_sizes, int n_in,
                              void* d_out, int out_size, void* d_ws, size_t ws_size,
                              hipStream_t stream) {
    const float* h_current = (const float*)d_in[0];  // [32,1024,18,32]
    const float* h_buffer  = (const float*)d_in[1];  // [8,32,1024,18,32]
    const float* W_qkv     = (const float*)d_in[2];  // [3072,1024]
    const float* W_out     = (const float*)d_in[3];  // [1024,1024]
    const float* b_out     = (const float*)d_in[4];  // [1024]
    const float* rel_emb   = (const float*)d_in[5];  // [17,8]

    ushort* ctxb = (ushort*)d_ws;                    // 294912 bf16
    ushort* Wb   = ctxb + 294912;                    // 3145728 bf16
    float* kvpart = (float*)(Wb + 3145728);          // 4 * 589824 fp32
    float* qpart  = kvpart + (size_t)NS * KV_MN;     // 4 * 32768
    float* attnb  = qpart + (size_t)NS * Q_MN;       // 32768
    // total ~16.7 MB

    // K1: pooling -> bf16 ctx (+ W_qkv bf16 conversion tail)
    pool_kernel<<<2048, 256, 0, stream>>>(h_buffer, h_current, W_qkv, ctxb, Wb);

    // K2: Q + KV projections via MFMA (304 blocks = 1216 wave-tiles)
    qkv_mfma<<<304, 256, 0, stream>>>(ctxb, Wb, qpart, kvpart);

    // K3: attention (256 single-wave blocks)
    attn_kernel<<<BB * NH, 64, 0, stream>>>(kvpart, qpart, rel_emb, attnb);

    // K4: fused out-projection + broadcast residual add
    final_fused<<<2048, 256, 0, stream>>>(h_current, attnb, W_out, b_out, (float*)d_out);
}

// Round 9
// 175.197 us; speedup vs baseline: 1.0810x; 1.0810x over previous
//
#include <hip/hip_runtime.h>
#include <hip/hip_bf16.h>

// Shapes (fixed by the reference)
#define BB 32          // batch
#define CC 1024        // channels
#define HWSZ 576       // H*W
#define KCTX 8         // CONTEXT_LEN
#define TT 9           // K+1
#define NH 8
#define HD 128

#define NS 4           // split-K for both projections (k-slice 256)
#define KV_MN (288 * 2048)
#define Q_MN  (32 * 1024)

typedef float v4f __attribute__((ext_vector_type(4)));
typedef __attribute__((ext_vector_type(8))) short  bf16x8;
typedef __attribute__((ext_vector_type(8))) ushort u16x8;
typedef __attribute__((ext_vector_type(4))) float  f32x4;

__device__ __forceinline__ ushort f2bf(float f) {
    uint u = __builtin_bit_cast(uint, f);
    return (ushort)((u + 0x7FFFu + ((u >> 16) & 1u)) >> 16);   // RNE
}

// ---------------------------------------------------------------------------
// K1: spatial mean pooling -> context [B][T][C] bf16, + W_qkv fp32->bf16 tail.
// NT loads on the 604 MB h_buffer stream (R7/R8 A/B: +35 us — L3 allocate/
// evict churn throttles the stream otherwise). h_current rows last with
// cached loads: L3-resident for K4's re-read.
// ---------------------------------------------------------------------------
__global__ __launch_bounds__(256) void pool_kernel(
    const float* __restrict__ hbuf,   // [K][B][C][H][W]
    const float* __restrict__ hcur,   // [B][C][H][W]
    const float* __restrict__ Wqkv,   // [3072][1024] fp32
    ushort* __restrict__ ctxb,        // [B][T][C] bf16
    ushort* __restrict__ Wb)          // [3072][1024] bf16
{
    const int wave = threadIdx.x >> 6;
    const int lane = threadIdx.x & 63;
    const int sub  = lane >> 4;        // row-within-wave 0..3
    const int l16  = lane & 15;
    const int stride = gridDim.x * 16; // rows per full sweep
    const int nrows = BB * TT * CC;    // 294912

    for (int r0 = (blockIdx.x * 4 + wave) * 4; r0 < nrows; r0 += stride) {
        const int r = r0 + sub;
        v4f acc = {0.f, 0.f, 0.f, 0.f};
        int cidx;
        if (r < KCTX * BB * CC) {                 // buffer rows, memory order
            const v4f* s4 = (const v4f*)(hbuf + (size_t)r * HWSZ);
            const int t = r >> 15;
            const int b = (r >> 10) & 31;
            cidx = (b * TT + t) * CC + (r & (CC - 1));
#pragma unroll
            for (int j = 0; j < 9; ++j)
                acc += __builtin_nontemporal_load(s4 + l16 + 16 * j);
        } else {                                  // current rows, last, cached
            const int rc = r - KCTX * BB * CC;
            const v4f* s4 = (const v4f*)(hcur + (size_t)rc * HWSZ);
            cidx = ((rc >> 10) * TT + KCTX) * CC + (rc & (CC - 1));
#pragma unroll
            for (int j = 0; j < 9; ++j)
                acc += s4[l16 + 16 * j];
        }
        float sum = acc.x + acc.y + acc.z + acc.w;
        sum += __shfl_xor(sum, 1);
        sum += __shfl_xor(sum, 2);
        sum += __shfl_xor(sum, 4);
        sum += __shfl_xor(sum, 8);
        if (l16 == 0) ctxb[cidx] = f2bf(sum * (1.0f / 576.0f));
    }

    // W_qkv fp32 -> bf16 (3072*1024/8 = 393216 chunks of 8)
    const int nchunk = 3072 * 1024 / 8;
    for (int idx = blockIdx.x * 256 + threadIdx.x; idx < nchunk;
         idx += gridDim.x * 256) {
        const float* src = Wqkv + (size_t)idx * 8;
        v4f a = *(const v4f*)src;
        v4f b = *(const v4f*)(src + 4);
        u16x8 o;
        o[0] = f2bf(a.x); o[1] = f2bf(a.y); o[2] = f2bf(a.z); o[3] = f2bf(a.w);
        o[4] = f2bf(b.x); o[5] = f2bf(b.y); o[6] = f2bf(b.z); o[7] = f2bf(b.w);
        *(u16x8*)(Wb + (size_t)idx * 8) = o;
    }
}

// ---------------------------------------------------------------------------
// K2: Q + KV projections via bf16 MFMA (no LDS; A/B straight from L2).
// 1216 wave-tiles: [0,1152) KV (18 mt x 16 nt x 4 splits, tile 16x128),
// [1152,1216) Q (2 mt x 8 nt x 4 splits). Partials fp32.
// ---------------------------------------------------------------------------
__global__ __launch_bounds__(256) void qkv_mfma(
    const ushort* __restrict__ ctxb, const ushort* __restrict__ Wb,
    float* __restrict__ qpart, float* __restrict__ kvpart)
{
    const int wave = threadIdx.x >> 6;
    const int lane = threadIdx.x & 63;
    const int t = blockIdx.x * 4 + wave;   // 0..1215
    const int l15 = lane & 15;
    const int kg  = lane >> 4;             // 0..3

    const ushort* abase;
    const ushort* bbase;
    float* out;
    int ldy, outrow0, outcol0;

    if (t < 1152) {                        // KV tiles
        const int s  = t & 3;
        const int tt = t >> 2;             // 0..287
        const int mt = tt / 16, nt = tt % 16;
        const int k0 = s * 256;
        abase = ctxb + (size_t)(mt * 16 + l15) * 1024 + k0 + kg * 8;
        bbase = Wb + (size_t)(1024 + nt * 128 + l15) * 1024 + k0 + kg * 8;
        out = kvpart + (size_t)s * KV_MN;
        ldy = 2048;
        outrow0 = mt * 16 + kg * 4;
        outcol0 = nt * 128 + l15;
    } else {                               // Q tiles
        const int r  = t - 1152;           // 0..63
        const int s  = r & 3;
        const int tt = r >> 2;             // 0..15
        const int mt = tt >> 3, nt = tt & 7;
        const int k0 = s * 256;
        abase = ctxb + (size_t)((mt * 16 + l15) * 9 + 8) * 1024 + k0 + kg * 8;
        bbase = Wb + (size_t)(nt * 128 + l15) * 1024 + k0 + kg * 8;
        out = qpart + (size_t)s * Q_MN;
        ldy = 1024;
        outrow0 = mt * 16 + kg * 4;
        outcol0 = nt * 128 + l15;
    }

    f32x4 acc0 = {0,0,0,0}, acc1 = {0,0,0,0}, acc2 = {0,0,0,0}, acc3 = {0,0,0,0};
    f32x4 acc4 = {0,0,0,0}, acc5 = {0,0,0,0}, acc6 = {0,0,0,0}, acc7 = {0,0,0,0};

#pragma unroll
    for (int kk = 0; kk < 8; ++kk) {       // 8 k-steps of 32 (k-slice 256)
        bf16x8 a = *(const bf16x8*)(abase + kk * 32);
        const ushort* bp = bbase + kk * 32;
        bf16x8 b0 = *(const bf16x8*)(bp + 0 * 16 * 1024);
        bf16x8 b1 = *(const bf16x8*)(bp + 1 * 16 * 1024);
        bf16x8 b2 = *(const bf16x8*)(bp + 2 * 16 * 1024);
        bf16x8 b3 = *(const bf16x8*)(bp + 3 * 16 * 1024);
        bf16x8 b4 = *(const bf16x8*)(bp + 4 * 16 * 1024);
        bf16x8 b5 = *(const bf16x8*)(bp + 5 * 16 * 1024);
        bf16x8 b6 = *(const bf16x8*)(bp + 6 * 16 * 1024);
        bf16x8 b7 = *(const bf16x8*)(bp + 7 * 16 * 1024);
        acc0 = __builtin_amdgcn_mfma_f32_16x16x32_bf16(a, b0, acc0, 0, 0, 0);
        acc1 = __builtin_amdgcn_mfma_f32_16x16x32_bf16(a, b1, acc1, 0, 0, 0);
        acc2 = __builtin_amdgcn_mfma_f32_16x16x32_bf16(a, b2, acc2, 0, 0, 0);
        acc3 = __builtin_amdgcn_mfma_f32_16x16x32_bf16(a, b3, acc3, 0, 0, 0);
        acc4 = __builtin_amdgcn_mfma_f32_16x16x32_bf16(a, b4, acc4, 0, 0, 0);
        acc5 = __builtin_amdgcn_mfma_f32_16x16x32_bf16(a, b5, acc5, 0, 0, 0);
        acc6 = __builtin_amdgcn_mfma_f32_16x16x32_bf16(a, b6, acc6, 0, 0, 0);
        acc7 = __builtin_amdgcn_mfma_f32_16x16x32_bf16(a, b7, acc7, 0, 0, 0);
    }

    float* yb = out + (size_t)outrow0 * ldy + outcol0;
#pragma unroll
    for (int i = 0; i < 4; ++i) {
        float* yr = yb + (size_t)i * ldy;
        yr[0 * 16] = acc0[i]; yr[1 * 16] = acc1[i];
        yr[2 * 16] = acc2[i]; yr[3 * 16] = acc3[i];
        yr[4 * 16] = acc4[i]; yr[5 * 16] = acc5[i];
        yr[6 * 16] = acc6[i]; yr[7 * 16] = acc7[i];
    }
}

// ---------------------------------------------------------------------------
// K3: attention, last query only. One wave per block, 256 blocks.
// Sums split-K partials of q and kv inline (L2-hot).
// ---------------------------------------------------------------------------
__global__ __launch_bounds__(64) void attn_kernel(
    const float* __restrict__ kvpart,   // NS slabs of [288][2048]
    const float* __restrict__ qpart,    // NS slabs of [32][1024]
    const float* __restrict__ rel_emb,  // [17][8]
    float* __restrict__ attn_out)       // [B][C]
{
    const int lane = threadIdx.x;
    const int pair = blockIdx.x;              // 0..255
    const int b = pair >> 3;
    const int h = pair & 7;
    const float scale = 0.08838834764831845f; // 1/sqrt(128)

    const int qoff = b * CC + h * HD;
    float q1 = 0.f, q2 = 0.f;
#pragma unroll
    for (int s = 0; s < NS; ++s) {
        q1 += qpart[(size_t)s * Q_MN + qoff + lane];
        q2 += qpart[(size_t)s * Q_MN + qoff + lane + 64];
    }
    q1 *= scale; q2 *= scale;

    float sc[TT];
#pragma unroll
    for (int j = 0; j < TT; ++j) {
        const size_t base = (size_t)(b * TT + j) * 2048 + h * HD;
        float k1 = 0.f, k2 = 0.f;
#pragma unroll
        for (int s = 0; s < NS; ++s) {
            k1 += kvpart[(size_t)s * KV_MN + base + lane];
            k2 += kvpart[(size_t)s * KV_MN + base + lane + 64];
        }
        float p = q1 * k1 + q2 * k2;
#pragma unroll
        for (int off = 32; off; off >>= 1) p += __shfl_xor(p, off);
        sc[j] = p + rel_emb[(2 * KCTX - j) * NH + h];
    }
    float m = sc[0];
#pragma unroll
    for (int j = 1; j < TT; ++j) m = fmaxf(m, sc[j]);
    float sum = 0.f;
#pragma unroll
    for (int j = 0; j < TT; ++j) { sc[j] = expf(sc[j] - m); sum += sc[j]; }
    const float inv = 1.0f / sum;

    float a1 = 0.f, a2 = 0.f;
#pragma unroll
    for (int j = 0; j < TT; ++j) {
        const size_t base = (size_t)(b * TT + j) * 2048 + 1024 + h * HD;
        float v1 = 0.f, v2 = 0.f;
#pragma unroll
        for (int s = 0; s < NS; ++s) {
            v1 += kvpart[(size_t)s * KV_MN + base + lane];
            v2 += kvpart[(size_t)s * KV_MN + base + lane + 64];
        }
        a1 += sc[j] * v1;
        a2 += sc[j] * v2;
    }
    attn_out[qoff + lane] = a1 * inv;
    attn_out[qoff + lane + 64] = a2 * inv;
}

// ---------------------------------------------------------------------------
// K4: c-major fused out-projection + broadcast residual add.
// One block per channel c: block computes out[0..31][c] cooperatively ONCE
// (Wout[c] row read once per block, broadcast across b; 32x less Wout L2
// traffic than per-wave dots), LDS-reduce, then 4 waves stream the 32 rows
// {b*1024+c} with a scalar add (no shfl in the stream path).
// ---------------------------------------------------------------------------
__global__ __launch_bounds__(256) void final_fused(
    const float* __restrict__ hc,       // [B][C][H][W]
    const float* __restrict__ attnb,    // [32][1024]
    const float* __restrict__ Wout,     // [1024][1024]
    const float* __restrict__ bias,     // [1024]
    float* __restrict__ y)
{
    __shared__ float partial[256];
    __shared__ float outs[BB];

    const int c = blockIdx.x;          // 0..1023
    const int t = threadIdx.x;
    const int b = t >> 3;              // 0..31
    const int seg = t & 7;             // 0..7  (128-float segment)

    // dot partial: attnb[b][seg*128 .. +128) . Wout[c][same]
    const v4f* ar = (const v4f*)(attnb + (size_t)b * CC + seg * 128);
    const v4f* wr = (const v4f*)(Wout + (size_t)c * CC + seg * 128);
    v4f acc = {0.f, 0.f, 0.f, 0.f};
#pragma unroll
    for (int j = 0; j < 32; ++j) acc += ar[j] * wr[j];
    partial[t] = acc.x + acc.y + acc.z + acc.w;
    __syncthreads();
    if (t < BB) {
        float s = 0.f;
#pragma unroll
        for (int i = 0; i < 8; ++i) s += partial[t * 8 + i];
        outs[t] = s + bias[c];
    }
    __syncthreads();

    // stream 32 rows: wave w handles b = w*8 .. w*8+7
    const int wave = t >> 6;
    const int lane = t & 63;
#pragma unroll
    for (int i = 0; i < 8; ++i) {
        const int bb = wave * 8 + i;
        const float add = outs[bb];
        const size_t r = (size_t)bb * CC + c;
        const v4f* s4 = (const v4f*)(hc + r * HWSZ);
        v4f* d4 = (v4f*)(y + r * HWSZ);
        v4f v0 = s4[lane];
        v0.x += add; v0.y += add; v0.z += add; v0.w += add;
        __builtin_nontemporal_store(v0, d4 + lane);
        v4f v1 = s4[lane + 64];
        v1.x += add; v1.y += add; v1.z += add; v1.w += add;
        __builtin_nontemporal_store(v1, d4 + lane + 64);
        if (lane < 16) {
            v4f v2 = s4[lane + 128];
            v2.x += add; v2.y += add; v2.z += add; v2.w += add;
            __builtin_nontemporal_store(v2, d4 + lane + 128);
        }
    }
}

// ---------------------------------------------------------------------------
extern "C" void kernel_launch(void* const* d_in, const int* in_sizes, int n_in,
                              void* d_out, int out_size, void* d_ws, size_t ws_size,
                              hipStream_t stream) {
    const float* h_current = (const float*)d_in[0];  // [32,1024,18,32]
    const float* h_buffer  = (const float*)d_in[1];  // [8,32,1024,18,32]
    const float* W_qkv     = (const float*)d_in[2];  // [3072,1024]
    const float* W_out     = (const float*)d_in[3];  // [1024,1024]
    const float* b_out     = (const float*)d_in[4];  // [1024]
    const float* rel_emb   = (const float*)d_in[5];  // [17,8]

    ushort* ctxb = (ushort*)d_ws;                    // 294912 bf16
    ushort* Wb   = ctxb + 294912;                    // 3145728 bf16
    float* kvpart = (float*)(Wb + 3145728);          // 4 * 589824 fp32
    float* qpart  = kvpart + (size_t)NS * KV_MN;     // 4 * 32768
    float* attnb  = qpart + (size_t)NS * Q_MN;       // 32768
    // total ~16.7 MB

    // K1: pooling -> bf16 ctx (+ W_qkv bf16 conversion tail), NT stream
    pool_kernel<<<2048, 256, 0, stream>>>(h_buffer, h_current, W_qkv, ctxb, Wb);

    // K2: Q + KV projections via MFMA (304 blocks = 1216 wave-tiles)
    qkv_mfma<<<304, 256, 0, stream>>>(ctxb, Wb, qpart, kvpart);

    // K3: attention (256 single-wave blocks)
    attn_kernel<<<BB * NH, 64, 0, stream>>>(kvpart, qpart, rel_emb, attnb);

    // K4: c-major fused out-projection + broadcast residual add
    final_fused<<<CC, 256, 0, stream>>>(h_current, attnb, W_out, b_out, (float*)d_out);
}

// Round 10
// 154.671 us; speedup vs baseline: 1.2245x; 1.1327x over previous
//
#include <hip/hip_runtime.h>
#include <hip/hip_bf16.h>

// Shapes (fixed by the reference)
#define BB 32          // batch
#define CC 1024        // channels
#define HWSZ 576       // H*W
#define KCTX 8         // CONTEXT_LEN
#define TT 9           // K+1
#define NH 8
#define HD 128

#define NS 4           // split-K for both projections (k-slice 256)
#define KV_MN (288 * 2048)
#define Q_MN  (32 * 1024)

typedef float v4f __attribute__((ext_vector_type(4)));
typedef __attribute__((ext_vector_type(8))) short  bf16x8;
typedef __attribute__((ext_vector_type(8))) ushort u16x8;
typedef __attribute__((ext_vector_type(4))) float  f32x4;

__device__ __forceinline__ ushort f2bf(float f) {
    uint u = __builtin_bit_cast(uint, f);
    return (ushort)((u + 0x7FFFu + ((u >> 16) & 1u)) >> 16);   // RNE
}

// ---------------------------------------------------------------------------
// K1: spatial mean pooling -> context [B][T][C] bf16, + W_qkv fp32->bf16 tail.
// NT loads on the 604 MB h_buffer stream (R7/R8 A/B: worth ~35 us — without
// them L3 allocate/evict churn throttles the stream). h_current rows last
// with cached loads: L3-resident for K4's re-read.
// ---------------------------------------------------------------------------
__global__ __launch_bounds__(256) void pool_kernel(
    const float* __restrict__ hbuf,   // [K][B][C][H][W]
    const float* __restrict__ hcur,   // [B][C][H][W]
    const float* __restrict__ Wqkv,   // [3072][1024] fp32
    ushort* __restrict__ ctxb,        // [B][T][C] bf16
    ushort* __restrict__ Wb)          // [3072][1024] bf16
{
    const int wave = threadIdx.x >> 6;
    const int lane = threadIdx.x & 63;
    const int sub  = lane >> 4;        // row-within-wave 0..3
    const int l16  = lane & 15;
    const int stride = gridDim.x * 16; // rows per full sweep
    const int nrows = BB * TT * CC;    // 294912

    for (int r0 = (blockIdx.x * 4 + wave) * 4; r0 < nrows; r0 += stride) {
        const int r = r0 + sub;
        v4f acc = {0.f, 0.f, 0.f, 0.f};
        int cidx;
        if (r < KCTX * BB * CC) {                 // buffer rows, memory order
            const v4f* s4 = (const v4f*)(hbuf + (size_t)r * HWSZ);
            const int t = r >> 15;
            const int b = (r >> 10) & 31;
            cidx = (b * TT + t) * CC + (r & (CC - 1));
#pragma unroll
            for (int j = 0; j < 9; ++j)
                acc += __builtin_nontemporal_load(s4 + l16 + 16 * j);
        } else {                                  // current rows, last, cached
            const int rc = r - KCTX * BB * CC;
            const v4f* s4 = (const v4f*)(hcur + (size_t)rc * HWSZ);
            cidx = ((rc >> 10) * TT + KCTX) * CC + (rc & (CC - 1));
#pragma unroll
            for (int j = 0; j < 9; ++j)
                acc += s4[l16 + 16 * j];
        }
        float sum = acc.x + acc.y + acc.z + acc.w;
        sum += __shfl_xor(sum, 1);
        sum += __shfl_xor(sum, 2);
        sum += __shfl_xor(sum, 4);
        sum += __shfl_xor(sum, 8);
        if (l16 == 0) ctxb[cidx] = f2bf(sum * (1.0f / 576.0f));
    }

    // W_qkv fp32 -> bf16 (3072*1024/8 = 393216 chunks of 8)
    const int nchunk = 3072 * 1024 / 8;
    for (int idx = blockIdx.x * 256 + threadIdx.x; idx < nchunk;
         idx += gridDim.x * 256) {
        const float* src = Wqkv + (size_t)idx * 8;
        v4f a = *(const v4f*)src;
        v4f b = *(const v4f*)(src + 4);
        u16x8 o;
        o[0] = f2bf(a.x); o[1] = f2bf(a.y); o[2] = f2bf(a.z); o[3] = f2bf(a.w);
        o[4] = f2bf(b.x); o[5] = f2bf(b.y); o[6] = f2bf(b.z); o[7] = f2bf(b.w);
        *(u16x8*)(Wb + (size_t)idx * 8) = o;
    }
}

// ---------------------------------------------------------------------------
// K2: Q + KV projections via bf16 MFMA (no LDS; A/B straight from L2).
// 1216 wave-tiles: [0,1152) KV (18 mt x 16 nt x 4 splits, tile 16x128),
// [1152,1216) Q (2 mt x 8 nt x 4 splits). Partials fp32.
// ---------------------------------------------------------------------------
__global__ __launch_bounds__(256) void qkv_mfma(
    const ushort* __restrict__ ctxb, const ushort* __restrict__ Wb,
    float* __restrict__ qpart, float* __restrict__ kvpart)
{
    const int wave = threadIdx.x >> 6;
    const int lane = threadIdx.x & 63;
    const int t = blockIdx.x * 4 + wave;   // 0..1215
    const int l15 = lane & 15;
    const int kg  = lane >> 4;             // 0..3

    const ushort* abase;
    const ushort* bbase;
    float* out;
    int ldy, outrow0, outcol0;

    if (t < 1152) {                        // KV tiles
        const int s  = t & 3;
        const int tt = t >> 2;             // 0..287
        const int mt = tt / 16, nt = tt % 16;
        const int k0 = s * 256;
        abase = ctxb + (size_t)(mt * 16 + l15) * 1024 + k0 + kg * 8;
        bbase = Wb + (size_t)(1024 + nt * 128 + l15) * 1024 + k0 + kg * 8;
        out = kvpart + (size_t)s * KV_MN;
        ldy = 2048;
        outrow0 = mt * 16 + kg * 4;
        outcol0 = nt * 128 + l15;
    } else {                               // Q tiles
        const int r  = t - 1152;           // 0..63
        const int s  = r & 3;
        const int tt = r >> 2;             // 0..15
        const int mt = tt >> 3, nt = tt & 7;
        const int k0 = s * 256;
        abase = ctxb + (size_t)((mt * 16 + l15) * 9 + 8) * 1024 + k0 + kg * 8;
        bbase = Wb + (size_t)(nt * 128 + l15) * 1024 + k0 + kg * 8;
        out = qpart + (size_t)s * Q_MN;
        ldy = 1024;
        outrow0 = mt * 16 + kg * 4;
        outcol0 = nt * 128 + l15;
    }

    f32x4 acc0 = {0,0,0,0}, acc1 = {0,0,0,0}, acc2 = {0,0,0,0}, acc3 = {0,0,0,0};
    f32x4 acc4 = {0,0,0,0}, acc5 = {0,0,0,0}, acc6 = {0,0,0,0}, acc7 = {0,0,0,0};

#pragma unroll
    for (int kk = 0; kk < 8; ++kk) {       // 8 k-steps of 32 (k-slice 256)
        bf16x8 a = *(const bf16x8*)(abase + kk * 32);
        const ushort* bp = bbase + kk * 32;
        bf16x8 b0 = *(const bf16x8*)(bp + 0 * 16 * 1024);
        bf16x8 b1 = *(const bf16x8*)(bp + 1 * 16 * 1024);
        bf16x8 b2 = *(const bf16x8*)(bp + 2 * 16 * 1024);
        bf16x8 b3 = *(const bf16x8*)(bp + 3 * 16 * 1024);
        bf16x8 b4 = *(const bf16x8*)(bp + 4 * 16 * 1024);
        bf16x8 b5 = *(const bf16x8*)(bp + 5 * 16 * 1024);
        bf16x8 b6 = *(const bf16x8*)(bp + 6 * 16 * 1024);
        bf16x8 b7 = *(const bf16x8*)(bp + 7 * 16 * 1024);
        acc0 = __builtin_amdgcn_mfma_f32_16x16x32_bf16(a, b0, acc0, 0, 0, 0);
        acc1 = __builtin_amdgcn_mfma_f32_16x16x32_bf16(a, b1, acc1, 0, 0, 0);
        acc2 = __builtin_amdgcn_mfma_f32_16x16x32_bf16(a, b2, acc2, 0, 0, 0);
        acc3 = __builtin_amdgcn_mfma_f32_16x16x32_bf16(a, b3, acc3, 0, 0, 0);
        acc4 = __builtin_amdgcn_mfma_f32_16x16x32_bf16(a, b4, acc4, 0, 0, 0);
        acc5 = __builtin_amdgcn_mfma_f32_16x16x32_bf16(a, b5, acc5, 0, 0, 0);
        acc6 = __builtin_amdgcn_mfma_f32_16x16x32_bf16(a, b6, acc6, 0, 0, 0);
        acc7 = __builtin_amdgcn_mfma_f32_16x16x32_bf16(a, b7, acc7, 0, 0, 0);
    }

    float* yb = out + (size_t)outrow0 * ldy + outcol0;
#pragma unroll
    for (int i = 0; i < 4; ++i) {
        float* yr = yb + (size_t)i * ldy;
        yr[0 * 16] = acc0[i]; yr[1 * 16] = acc1[i];
        yr[2 * 16] = acc2[i]; yr[3 * 16] = acc3[i];
        yr[4 * 16] = acc4[i]; yr[5 * 16] = acc5[i];
        yr[6 * 16] = acc6[i]; yr[7 * 16] = acc7[i];
    }
}

// ---------------------------------------------------------------------------
// K3: attention, last query only. One wave per block, 256 blocks.
// Sums split-K partials of q and kv inline (L2-hot).
// ---------------------------------------------------------------------------
__global__ __launch_bounds__(64) void attn_kernel(
    const float* __restrict__ kvpart,   // NS slabs of [288][2048]
    const float* __restrict__ qpart,    // NS slabs of [32][1024]
    const float* __restrict__ rel_emb,  // [17][8]
    float* __restrict__ attn_out)       // [B][C]
{
    const int lane = threadIdx.x;
    const int pair = blockIdx.x;              // 0..255
    const int b = pair >> 3;
    const int h = pair & 7;
    const float scale = 0.08838834764831845f; // 1/sqrt(128)

    const int qoff = b * CC + h * HD;
    float q1 = 0.f, q2 = 0.f;
#pragma unroll
    for (int s = 0; s < NS; ++s) {
        q1 += qpart[(size_t)s * Q_MN + qoff + lane];
        q2 += qpart[(size_t)s * Q_MN + qoff + lane + 64];
    }
    q1 *= scale; q2 *= scale;

    float sc[TT];
#pragma unroll
    for (int j = 0; j < TT; ++j) {
        const size_t base = (size_t)(b * TT + j) * 2048 + h * HD;
        float k1 = 0.f, k2 = 0.f;
#pragma unroll
        for (int s = 0; s < NS; ++s) {
            k1 += kvpart[(size_t)s * KV_MN + base + lane];
            k2 += kvpart[(size_t)s * KV_MN + base + lane + 64];
        }
        float p = q1 * k1 + q2 * k2;
#pragma unroll
        for (int off = 32; off; off >>= 1) p += __shfl_xor(p, off);
        sc[j] = p + rel_emb[(2 * KCTX - j) * NH + h];
    }
    float m = sc[0];
#pragma unroll
    for (int j = 1; j < TT; ++j) m = fmaxf(m, sc[j]);
    float sum = 0.f;
#pragma unroll
    for (int j = 0; j < TT; ++j) { sc[j] = expf(sc[j] - m); sum += sc[j]; }
    const float inv = 1.0f / sum;

    float a1 = 0.f, a2 = 0.f;
#pragma unroll
    for (int j = 0; j < TT; ++j) {
        const size_t base = (size_t)(b * TT + j) * 2048 + 1024 + h * HD;
        float v1 = 0.f, v2 = 0.f;
#pragma unroll
        for (int s = 0; s < NS; ++s) {
            v1 += kvpart[(size_t)s * KV_MN + base + lane];
            v2 += kvpart[(size_t)s * KV_MN + base + lane + 64];
        }
        a1 += sc[j] * v1;
        a2 += sc[j] * v2;
    }
    attn_out[qoff + lane] = a1 * inv;
    attn_out[qoff + lane + 64] = a2 * inv;
}

// ---------------------------------------------------------------------------
// K4: fused out-projection + broadcast residual add (R5/R7-proven per-wave,
// memory-ordered sweep; best of 4 tested variants). One wave per output row:
// dot(attnb[b,:], Wout[c,:]) from L2, + bias, broadcast-add over 576 spatial
// floats (L3-hot h_current read), NT store to y.
// ---------------------------------------------------------------------------
__global__ __launch_bounds__(256) void final_fused(
    const float* __restrict__ hc,       // [B][C][H][W]
    const float* __restrict__ attnb,    // [32][1024]
    const float* __restrict__ Wout,     // [1024][1024]
    const float* __restrict__ bias,     // [1024]
    float* __restrict__ y)
{
    const int wave = threadIdx.x >> 6;
    const int lane = threadIdx.x & 63;
    const int stride = gridDim.x * 4;
    const int nrows = BB * CC;

    for (int r = blockIdx.x * 4 + wave; r < nrows; r += stride) {
        const int b = r >> 10;
        const int c = r & (CC - 1);

        const v4f* ar = (const v4f*)(attnb + (size_t)b * CC);
        const v4f* wr = (const v4f*)(Wout + (size_t)c * CC);
        v4f acc = {0.f, 0.f, 0.f, 0.f};
#pragma unroll
        for (int j = 0; j < 4; ++j) {
            v4f a = ar[lane + 64 * j];
            v4f w = wr[lane + 64 * j];
            acc += a * w;
        }
        float dot = acc.x + acc.y + acc.z + acc.w;
#pragma unroll
        for (int off = 32; off; off >>= 1) dot += __shfl_xor(dot, off);
        const float add = dot + bias[c];

        const v4f* s4 = (const v4f*)(hc + (size_t)r * HWSZ);
        v4f* d4 = (v4f*)(y + (size_t)r * HWSZ);
        v4f v0 = s4[lane];
        v0.x += add; v0.y += add; v0.z += add; v0.w += add;
        __builtin_nontemporal_store(v0, d4 + lane);
        v4f v1 = s4[lane + 64];
        v1.x += add; v1.y += add; v1.z += add; v1.w += add;
        __builtin_nontemporal_store(v1, d4 + lane + 64);
        if (lane < 16) {
            v4f v2 = s4[lane + 128];
            v2.x += add; v2.y += add; v2.z += add; v2.w += add;
            __builtin_nontemporal_store(v2, d4 + lane + 128);
        }
    }
}

// ---------------------------------------------------------------------------
extern "C" void kernel_launch(void* const* d_in, const int* in_sizes, int n_in,
                              void* d_out, int out_size, void* d_ws, size_t ws_size,
                              hipStream_t stream) {
    const float* h_current = (const float*)d_in[0];  // [32,1024,18,32]
    const float* h_buffer  = (const float*)d_in[1];  // [8,32,1024,18,32]
    const float* W_qkv     = (const float*)d_in[2];  // [3072,1024]
    const float* W_out     = (const float*)d_in[3];  // [1024,1024]
    const float* b_out     = (const float*)d_in[4];  // [1024]
    const float* rel_emb   = (const float*)d_in[5];  // [17,8]

    ushort* ctxb = (ushort*)d_ws;                    // 294912 bf16
    ushort* Wb   = ctxb + 294912;                    // 3145728 bf16
    float* kvpart = (float*)(Wb + 3145728);          // 4 * 589824 fp32
    float* qpart  = kvpart + (size_t)NS * KV_MN;     // 4 * 32768
    float* attnb  = qpart + (size_t)NS * Q_MN;       // 32768
    // total ~16.7 MB

    // K1: pooling -> bf16 ctx (+ W_qkv bf16 conversion tail), NT stream
    pool_kernel<<<2048, 256, 0, stream>>>(h_buffer, h_current, W_qkv, ctxb, Wb);

    // K2: Q + KV projections via MFMA (304 blocks = 1216 wave-tiles)
    qkv_mfma<<<304, 256, 0, stream>>>(ctxb, Wb, qpart, kvpart);

    // K3: attention (256 single-wave blocks)
    attn_kernel<<<BB * NH, 64, 0, stream>>>(kvpart, qpart, rel_emb, attnb);

    // K4: fused out-projection + broadcast residual add (per-wave, R7 form)
    final_fused<<<2048, 256, 0, stream>>>(h_current, attnb, W_out, b_out, (float*)d_out);
}